// Round 1
// 158.430 us; speedup vs baseline: 1.1032x; 1.1032x over previous
//
#include <hip/hip_runtime.h>

#pragma clang fp contract(off)

typedef __attribute__((ext_vector_type(8))) short short8;
typedef __attribute__((ext_vector_type(4))) float f32x4;

#define MARGIN 0.02f

static __device__ __forceinline__ unsigned short f2b(float f) {
    union { float f; unsigned u; } x; x.f = f;
    unsigned u = x.u;
    return (unsigned short)((u + 0x7FFFu + ((u >> 16) & 1u)) >> 16);
}

// Bit-exact np distance: dot = single-accumulator ascending-k FMA chain
// (BLAS sgemm micro-kernel order) on FULL-PRECISION fp32 z from global;
// d = (zn - 2*dot) + en, each op single-rounded fp32.
// ES = element stride of the codebook column (1 for Et, 1024 for E).
template <int ES>
static __device__ __forceinline__ float np_dist(
    const float* __restrict__ zr, const float* __restrict__ ecol,
    float zn, float en) {
    float c = 0.f;
    #pragma unroll
    for (int i = 0; i < 64; ++i) c = fmaf(zr[i], ecol[i * ES], c);
    float t = zn - 2.f * c;
    return t + en;
}

// ---------------------------------------------------------------------------
// Merged prep kernel (grid 256 x 256):
//  - Et[k*64+d] transpose (fp32) for exact re-eval + gather        [if ET]
//  - Eb: bf16 codebook pre-converted & pre-swizzled in the EXACT
//    byte layout vq_main stages into LDS (8 tiles x 16 KB)          [if EB]
//  - enorm[k]: ascending-d fmaf chain (np axis-0 reduce order)
//  - zero the loss accumulator
// Eb layout check vs vq_main's staging write
//   byte = col*128 + ((d0>>3)^(col&7))*16 + (d0&7)*2 :
//   u32 word t -> st=t>>12, col=(t&4095)>>5, w=t&31, g=w>>2,
//   d0=((g^(col&7))<<3)|((w&3)<<1)  => byte 4w = g*16+(w&3)*4  (matches).
// ---------------------------------------------------------------------------
template <bool ET, bool EB>
__global__ __launch_bounds__(256) void vq_prep_all(
    const float* __restrict__ E, float* __restrict__ ws_loss,
    float* __restrict__ enorm, float* __restrict__ Et,
    unsigned* __restrict__ EbW) {
    const int t = blockIdx.x * 256 + threadIdx.x;  // 0..65535
    if (ET) {
        Et[t] = E[(t & 63) * 1024 + (t >> 6)];
    }
    if (EB) {
        if (t < 32768) {
            const int st = t >> 12;
            const int r = t & 4095;
            const int col = r >> 5;
            const int w = r & 31;
            const int g = w >> 2;
            const int d0 = ((g ^ (col & 7)) << 3) | ((w & 3) << 1);
            const int gc = st * 128 + col;
            const unsigned lo = f2b(E[d0 * 1024 + gc]);
            const unsigned hi = f2b(E[(d0 + 1) * 1024 + gc]);
            EbW[t] = lo | (hi << 16);
        }
    }
    if (t < 1024) {
        const float* colp = E + t;
        float s2 = 0.f;
        #pragma unroll
        for (int d = 0; d < 64; ++d) {
            float v = colp[d * 1024];
            s2 = fmaf(v, v, s2);
        }
        enorm[t] = s2;
        if (t == 0) *ws_loss = 0.f;
    }
}

// ---------------------------------------------------------------------------
// Main kernel: MFMA screening with PACKED top-2 (tile index in low 6 mantissa
// bits; perturbation ~4e-6 << MARGIN=0.02) -> min/med3 update (4 VALU/value
// vs 9 before). Codebook staged from precomputed Eb via double-buffered LDS
// with async-split copy (loads issued before compute, writes after).
// Exact fp32 re-eval + gather + loss unchanged (bit-exact np semantics).
// Block = 256 (4 waves), 128 rows, grid = 1024. LDS ~37 KB -> 4 blocks/CU.
// ---------------------------------------------------------------------------
template <bool USE_ET, bool USE_EB>
__global__ __launch_bounds__(256) void vq_main(
    const float* __restrict__ z, const float* __restrict__ E,
    const float* __restrict__ Et, const unsigned short* __restrict__ Eb,
    const float* __restrict__ enorm,
    float* __restrict__ ws_loss, float* __restrict__ out) {
    __shared__ unsigned short sB[2][128 * 64];  // 2 x 16 KB swizzled bf16 B-tiles
    __shared__ float sEn[1024];
    __shared__ float sZn[128];
    __shared__ int sIdx[128];
    __shared__ float sRed[4];

    const int tid = threadIdx.x;
    const int w = tid >> 6;
    const int l = tid & 63;
    const int quad = l >> 4;
    const int m = l & 15;
    const int b = blockIdx.x;

    ((float4*)sEn)[tid] = ((const float4*)enorm)[tid];

    // znorm: bit-exact numpy pairwise sum (SSE path, 4 accumulators, hadd).
    if (tid < 128) {
        const float* zr = z + (b * 128 + tid) * 64;
        float S[16];
        #pragma unroll
        for (int u = 0; u < 16; ++u) { float v = zr[u]; S[u] = v * v; }
        #pragma unroll
        for (int t = 1; t < 4; ++t)
            #pragma unroll
            for (int u = 0; u < 16; ++u) {
                float v = zr[16 * t + u];
                float sq = v * v;
                S[u] = S[u] + sq;
            }
        float R0 = (S[0] + S[4]) + (S[8] + S[12]);
        float R1 = (S[1] + S[5]) + (S[9] + S[13]);
        float R2 = (S[2] + S[6]) + (S[10] + S[14]);
        float R3 = (S[3] + S[7]) + (S[11] + S[15]);
        sZn[tid] = (R0 + R1) + (R2 + R3);
    }

    // A fragments (fp32 -> bf16 RNE for the screening MFMA)
    short8 a[2][2];
    #pragma unroll
    for (int rt = 0; rt < 2; ++rt) {
        const int rowl = w * 32 + rt * 16 + m;
        #pragma unroll
        for (int s = 0; s < 2; ++s) {
            const float* zp = z + (b * 128 + rowl) * 64 + s * 32 + quad * 8;
            union { float4 v; float f[4]; } u0, u1;
            u0.v = *(const float4*)zp;
            u1.v = *(const float4*)(zp + 4);
            short8 av;
            #pragma unroll
            for (int j = 0; j < 4; ++j) av[j] = (short)f2b(u0.f[j]);
            #pragma unroll
            for (int j = 0; j < 4; ++j) av[4 + j] = (short)f2b(u1.f[j]);
            a[rt][s] = av;
        }
    }

    // packed top-2 per lane-slot: value with tile index c in low 6 bits
    float v1p[2][4], v2p[2][4];
    #pragma unroll
    for (int rt = 0; rt < 2; ++rt)
        #pragma unroll
        for (int r = 0; r < 4; ++r) { v1p[rt][r] = 3.4e38f; v2p[rt][r] = 3.4e38f; }

    short8 nx0, nx1, nx2, nx3;
    if (USE_EB) {
        // prologue: tile 0 -> buf 0 (pure 16 KB copy, layout precomputed)
        const short8* s0 = (const short8*)Eb;
        short8* dp = (short8*)sB[0];
        #pragma unroll
        for (int i = 0; i < 4; ++i) dp[tid + i * 256] = s0[tid + i * 256];
        __syncthreads();
    }

    for (int st = 0; st < 8; ++st) {
        const unsigned short* sBc;
        if (USE_EB) {
            if (st < 7) {  // issue next-tile loads early (hide under compute)
                const short8* sn = (const short8*)(Eb + (st + 1) * 8192);
                nx0 = sn[tid];
                nx1 = sn[tid + 256];
                nx2 = sn[tid + 512];
                nx3 = sn[tid + 768];
            }
            sBc = sB[st & 1];
        } else {
            // fallback: in-kernel fp32->bf16 conversion + swizzle (original)
            #pragma unroll
            for (int i = 0; i < 4; ++i) {
                const int u = tid + i * 256;       // 0..1023
                const int d0 = (u & 31) * 2;
                const int cg = u >> 5;             // 0..31 (4 cols each)
                const float* e0 = E + d0 * 1024 + st * 128 + cg * 4;
                union { float4 v; float f[4]; } va, vb;
                va.v = *(const float4*)e0;
                vb.v = *(const float4*)(e0 + 1024);
                #pragma unroll
                for (int j = 0; j < 4; ++j) {
                    const int col = cg * 4 + j;    // local col 0..127
                    const unsigned lo = f2b(va.f[j]);
                    const unsigned hi = f2b(vb.f[j]);
                    const int gi = col * 8 + ((d0 >> 3) ^ (col & 7));
                    *(unsigned*)&sB[0][gi * 8 + (d0 & 7)] = lo | (hi << 16);
                }
            }
            __syncthreads();
            sBc = sB[0];
        }

        #pragma unroll
        for (int ct = 0; ct < 8; ++ct) {
            const int c = st * 8 + ct;             // global 16-col tile 0..63
            const int colb = (ct * 16 + m) * 8;
            short8 b0 = *(const short8*)&sBc[(colb + (quad ^ (m & 7))) * 8];
            short8 b1 = *(const short8*)&sBc[(colb + ((4 + quad) ^ (m & 7))) * 8];
            f32x4 acc0 = {0.f, 0.f, 0.f, 0.f};
            f32x4 acc1 = {0.f, 0.f, 0.f, 0.f};
            acc0 = __builtin_amdgcn_mfma_f32_16x16x32_bf16(a[0][0], b0, acc0, 0, 0, 0);
            acc0 = __builtin_amdgcn_mfma_f32_16x16x32_bf16(a[0][1], b1, acc0, 0, 0, 0);
            acc1 = __builtin_amdgcn_mfma_f32_16x16x32_bf16(a[1][0], b0, acc1, 0, 0, 0);
            acc1 = __builtin_amdgcn_mfma_f32_16x16x32_bf16(a[1][1], b1, acc1, 0, 0, 0);
            const float en = sEn[c * 16 + m];
            #pragma unroll
            for (int r = 0; r < 4; ++r) {
                // pack tile index into low 6 mantissa bits (v_and_or_b32),
                // then top-2 via med3 + min (order matters: med3 first)
                float p0 = fmaf(-2.f, acc0[r], en);
                p0 = __uint_as_float((__float_as_uint(p0) & 0xFFFFFFC0u) | (unsigned)c);
                v2p[0][r] = __builtin_amdgcn_fmed3f(p0, v1p[0][r], v2p[0][r]);
                v1p[0][r] = fminf(p0, v1p[0][r]);
                float p1 = fmaf(-2.f, acc1[r], en);
                p1 = __uint_as_float((__float_as_uint(p1) & 0xFFFFFFC0u) | (unsigned)c);
                v2p[1][r] = __builtin_amdgcn_fmed3f(p1, v1p[1][r], v2p[1][r]);
                v1p[1][r] = fminf(p1, v1p[1][r]);
            }
        }

        if (USE_EB) {
            if (st < 7) {  // write next tile late (loads had compute to land)
                short8* dn = (short8*)sB[(st & 1) ^ 1];
                dn[tid] = nx0;
                dn[tid + 256] = nx1;
                dn[tid + 512] = nx2;
                dn[tid + 768] = nx3;
            }
            __syncthreads();
        } else {
            __syncthreads();
        }
    }

    // exact re-evaluation (fp32 z from global, E column from Et/E);
    // lexicographic (d, k) min = np first-occurrence tie-break
    float la = 0.f;
    #pragma unroll
    for (int rt = 0; rt < 2; ++rt) {
        #pragma unroll
        for (int r = 0; r < 4; ++r) {
            float pv1 = v1p[rt][r];
            float vb = pv1;
            #pragma unroll
            for (int mask = 1; mask <= 8; mask <<= 1)
                vb = fminf(vb, __shfl_xor(vb, mask));
            const int rowl = w * 32 + rt * 16 + quad * 4 + r;
            const float zn = sZn[rowl];
            const float* zr = z + (b * 128 + rowl) * 64;
            float d = 3.4e38f;
            int kk = 0x7fffffff;
            if (pv1 <= vb + MARGIN) {
                kk = (int)(__float_as_uint(pv1) & 63u) * 16 + m;
                d = USE_ET ? np_dist<1>(zr, Et + kk * 64, zn, sEn[kk])
                           : np_dist<1024>(zr, E + kk, zn, sEn[kk]);
            }
            float pv2 = v2p[rt][r];
            if (pv2 <= vb + MARGIN) {
                int kc = (int)(__float_as_uint(pv2) & 63u) * 16 + m;
                float dd = USE_ET ? np_dist<1>(zr, Et + kc * 64, zn, sEn[kc])
                                  : np_dist<1024>(zr, E + kc, zn, sEn[kc]);
                if (dd < d || (dd == d && kc < kk)) { d = dd; kk = kc; }
            }
            #pragma unroll
            for (int mask = 1; mask <= 8; mask <<= 1) {
                float d2 = __shfl_xor(d, mask);
                int c2 = __shfl_xor(kk, mask);
                bool take = (d2 < d) || (d2 == d && c2 < kk);
                d = take ? d2 : d;
                kk = take ? c2 : kk;
            }
            if (m == 0) {
                sIdx[rowl] = kk;
                la += d;
            }
        }
    }
    __syncthreads();

    // gather: 2 lanes/row, 32 dims each (contiguous from Et when available)
    {
        const int row_local = w * 32 + (l >> 1);
        const int half = l & 1;
        const int idx = sIdx[row_local];
        union { float s[32]; float4 f[8]; } tmp;
        if (USE_ET) {
            const float4* src = (const float4*)(Et + idx * 64 + half * 32);
            #pragma unroll
            for (int q4 = 0; q4 < 8; ++q4) tmp.f[q4] = src[q4];
        } else {
            #pragma unroll
            for (int dd = 0; dd < 32; ++dd) tmp.s[dd] = E[(half * 32 + dd) * 1024 + idx];
        }
        float4* dst = (float4*)(out + (b * 128 + row_local) * 64 + half * 32);
        #pragma unroll
        for (int q4 = 0; q4 < 8; ++q4) dst[q4] = tmp.f[q4];
    }

    #pragma unroll
    for (int mask = 32; mask >= 1; mask >>= 1) la += __shfl_xor(la, mask);
    if (l == 0) sRed[w] = la;
    __syncthreads();
    if (tid == 0) atomicAdd(ws_loss, sRed[0] + sRed[1] + sRed[2] + sRed[3]);
}

// ---------------------------------------------------------------------------
// Final: loss scalar (fp32) at out[8388608]
// ---------------------------------------------------------------------------
__global__ void vq_final(const float* __restrict__ ws_loss,
                         float* __restrict__ out) {
    out[8388608] = (*ws_loss) * (1.25f / 8388608.f);
}

extern "C" void kernel_launch(void* const* d_in, const int* in_sizes, int n_in,
                              void* d_out, int out_size, void* d_ws, size_t ws_size,
                              hipStream_t stream) {
    const float* z = (const float*)d_in[0];  // fp32 [131072,64]
    const float* E = (const float*)d_in[1];  // fp32 [64,1024]
    float* out = (float*)d_out;              // fp32 [8388609]

    char* ws = (char*)d_ws;
    float* loss = (float*)ws;                          // 4 B
    float* enorm = (float*)(ws + 128);                 // 4 KB
    unsigned short* Eb = (unsigned short*)(ws + 8192); // 128 KB bf16 swizzled
    float* Et = (float*)(ws + 139264);                 // 256 KB fp32 transpose
    const bool useEb = ws_size >= (size_t)139264;
    const bool useEt = ws_size >= (size_t)401408;

    if (useEt) {
        vq_prep_all<true, true><<<256, 256, 0, stream>>>(E, loss, enorm, Et, (unsigned*)Eb);
        vq_main<true, true><<<1024, 256, 0, stream>>>(z, E, Et, Eb, enorm, loss, out);
    } else if (useEb) {
        vq_prep_all<false, true><<<256, 256, 0, stream>>>(E, loss, enorm, Et, (unsigned*)Eb);
        vq_main<false, true><<<1024, 256, 0, stream>>>(z, E, Et, Eb, enorm, loss, out);
    } else {
        vq_prep_all<false, false><<<256, 256, 0, stream>>>(E, loss, enorm, Et, (unsigned*)Eb);
        vq_main<false, false><<<1024, 256, 0, stream>>>(z, E, Et, Eb, enorm, loss, out);
    }
    vq_final<<<1, 1, 0, stream>>>(loss, out);
}